// Round 3
// baseline (113.790 us; speedup 1.0000x reference)
//
#include <hip/hip_runtime.h>

// YOLO loss on MI355X — round 10: resubmit of R9 (round-2 bench died to an
// infra failure — "container failed twice" — with no compile/correctness
// signal; kernel re-audited: bounds clean, no loops, no DMA choreography).
//
// R9 rationale: R4 (reg->LDS, 10 blk/CU) and R8 (global_load_lds ping-pong,
// 5 blk/CU) both sit at ~25 us = 3.7 TB/s useful read BW — two different
// staging engines, same number => the LDS stage/read structure itself is
// the limiter, not how loads are issued. This round uses the pair-alignment
// identity: 2 cells = 240 B = 15 float4 (16B-aligned). Even cell = pair-f4
// 0..7 (floats 0..31), odd cell = pair-f4 7..14 (floats 28..59). Each lane
// loads 8 aligned float4 per tensor straight to registers and extracts its
// cell with a static parity shift (v_cndmask only — no runtime-indexed
// arrays, no scratch). Structure becomes the m13 float4-copy shape:
// 256-thread blocks, 1568 blocks, ~16KB in flight per wave, no LDS stage.
// Predicted: cell kernel 25 -> ~16 us, FETCH stays ~96-103 MB, total ~104 us.

#define BLOCK 256

// Scalar fallback for an odd trailing cell (never taken for B*196 cells).
__device__ float cell_loss_ptr(const float* __restrict__ pv,
                               const float* __restrict__ tv) {
    float conf_t = tv[4];
    if (conf_t == 0.0f) {
        float d4 = pv[4] - tv[4];
        float d9 = pv[9] - tv[9];
        return 0.5f * (d4 * d4 + d9 * d9);
    }
    float cls = 0.0f;
#pragma unroll
    for (int c = 10; c < 30; ++c) {
        float d = pv[c] - tv[c];
        cls += d * d;
    }
    float t0x = tv[0] / 14.0f, t0y = tv[1] / 14.0f;
    float tx1 = t0x - 0.5f * tv[2], ty1 = t0y - 0.5f * tv[3];
    float tx2 = t0x + 0.5f * tv[2], ty2 = t0y + 0.5f * tv[3];
    float area_t = (tx2 - tx1) * (ty2 - ty1);
    float iou0, iou1;
#pragma unroll
    for (int b = 0; b < 2; ++b) {
        float bx = pv[5*b + 0] / 14.0f, by = pv[5*b + 1] / 14.0f;
        float px1 = bx - 0.5f * pv[5*b + 2], py1 = by - 0.5f * pv[5*b + 3];
        float px2 = bx + 0.5f * pv[5*b + 2], py2 = by + 0.5f * pv[5*b + 3];
        float ltx = fmaxf(px1, tx1), lty = fmaxf(py1, ty1);
        float rbx = fminf(px2, tx2), rby = fminf(py2, ty2);
        float iw = fmaxf(rbx - ltx, 0.0f), ih = fmaxf(rby - lty, 0.0f);
        float inter = iw * ih;
        float area_p = (px2 - px1) * (py2 - py1);
        float v = inter / (area_p + area_t - inter);
        if (b == 0) iou0 = v; else iou1 = v;
    }
    bool sel1 = iou1 > iou0;
    float max_iou = sel1 ? iou1 : iou0;
    float ps0 = sel1 ? pv[5] : pv[0];
    float ps1 = sel1 ? pv[6] : pv[1];
    float ps2 = sel1 ? pv[7] : pv[2];
    float ps3 = sel1 ? pv[8] : pv[3];
    float ps4 = sel1 ? pv[9] : pv[4];
    float ts0 = sel1 ? tv[5] : tv[0];
    float ts1 = sel1 ? tv[6] : tv[1];
    float ts2 = sel1 ? tv[7] : tv[2];
    float ts3 = sel1 ? tv[8] : tv[3];
    float notresp_conf = sel1 ? pv[4] : pv[9];
    float dconf = ps4 - max_iou;
    float dx = ps0 - ts0, dy = ps1 - ts1;
    float dw = sqrtf(ps2) - sqrtf(ts2);
    float dh = sqrtf(ps3) - sqrtf(ts3);
    float loc = dx * dx + dy * dy + dw * dw + dh * dh;
    return 5.0f * loc + 2.0f * dconf * dconf
         + notresp_conf * notresp_conf + cls;
}

__global__ __launch_bounds__(BLOCK, 4) void yolo_cell_kernel(
    const float* __restrict__ pred, const float* __restrict__ targ,
    float* __restrict__ block_sums, int n_cells)
{
    const int cell = blockIdx.x * BLOCK + threadIdx.x;
    const int n_fast = n_cells & ~1;   // pair path handles even count
    float loss = 0.0f;

    if (cell < n_fast) {
        const int pair = cell >> 1;
        const int par  = cell & 1;     // 0: pair-f4 0..7, 1: pair-f4 7..14
        const float4* gp = reinterpret_cast<const float4*>(pred)
                         + (size_t)pair * 15 + (par ? 7 : 0);
        const float4* gt = reinterpret_cast<const float4*>(targ)
                         + (size_t)pair * 15 + (par ? 7 : 0);

        float4 P0 = gp[0], P1 = gp[1], P2 = gp[2], P3 = gp[3];
        float4 P4 = gp[4], P5 = gp[5], P6 = gp[6], P7 = gp[7];
        float4 T0 = gt[0], T1 = gt[1], T2 = gt[2], T3 = gt[3];
        float4 T4 = gt[4], T5 = gt[5], T6 = gt[6], T7 = gt[7];

        // ---- class loss ----
        // Local slot s holds cell float s - 2*par. Cell floats 10..29 map to
        // slots 12..29 for BOTH parities, plus slots {10,11} (even) or
        // {30,31} (odd). Slots 12..29 = f4 3..6 full + f4 7 .x .y.
        float sA = 0.0f;
#define ACC2(a, b) { float d_ = (a) - (b); sA += d_ * d_; }
        ACC2(P3.x, T3.x); ACC2(P3.y, T3.y); ACC2(P3.z, T3.z); ACC2(P3.w, T3.w);
        ACC2(P4.x, T4.x); ACC2(P4.y, T4.y); ACC2(P4.z, T4.z); ACC2(P4.w, T4.w);
        ACC2(P5.x, T5.x); ACC2(P5.y, T5.y); ACC2(P5.z, T5.z); ACC2(P5.w, T5.w);
        ACC2(P6.x, T6.x); ACC2(P6.y, T6.y); ACC2(P6.z, T6.z); ACC2(P6.w, T6.w);
        ACC2(P7.x, T7.x); ACC2(P7.y, T7.y);
#undef ACC2
        float dlo0 = P2.z - T2.z, dlo1 = P2.w - T2.w;
        float c_lo = dlo0 * dlo0 + dlo1 * dlo1;
        float dhi0 = P7.z - T7.z, dhi1 = P7.w - T7.w;
        float c_hi = dhi0 * dhi0 + dhi1 * dhi1;
        float cls = sA + (par ? c_hi : c_lo);

        // ---- box floats 0..9 via static parity shift (+2 floats if odd) ----
        float bp0 = par ? P0.z : P0.x;
        float bp1 = par ? P0.w : P0.y;
        float bp2 = par ? P1.x : P0.z;
        float bp3 = par ? P1.y : P0.w;
        float bp4 = par ? P1.z : P1.x;
        float bp5 = par ? P1.w : P1.y;
        float bp6 = par ? P2.x : P1.z;
        float bp7 = par ? P2.y : P1.w;
        float bp8 = par ? P2.z : P2.x;
        float bp9 = par ? P2.w : P2.y;
        float bt0 = par ? T0.z : T0.x;
        float bt1 = par ? T0.w : T0.y;
        float bt2 = par ? T1.x : T0.z;
        float bt3 = par ? T1.y : T0.w;
        float bt4 = par ? T1.z : T1.x;
        float bt5 = par ? T1.w : T1.y;
        float bt6 = par ? T2.x : T1.z;
        float bt7 = par ? T2.y : T1.w;
        float bt8 = par ? T2.z : T2.x;
        float bt9 = par ? T2.w : T2.y;

        float conf_t = bt4;
        if (conf_t == 0.0f) {
            float d4 = bp4 - bt4;
            float d9 = bp9 - bt9;
            loss = 0.5f * (d4 * d4 + d9 * d9);
        } else {
            // target box 0 -> xyxy (mirror reference arithmetic exactly)
            float t0x = bt0 / 14.0f, t0y = bt1 / 14.0f;
            float tx1 = t0x - 0.5f * bt2, ty1 = t0y - 0.5f * bt3;
            float tx2 = t0x + 0.5f * bt2, ty2 = t0y + 0.5f * bt3;
            float area_t = (tx2 - tx1) * (ty2 - ty1);

            float iou0, iou1;
            {   // pred box 0: bp0..bp3
                float bx = bp0 / 14.0f, by = bp1 / 14.0f;
                float px1 = bx - 0.5f * bp2, py1 = by - 0.5f * bp3;
                float px2 = bx + 0.5f * bp2, py2 = by + 0.5f * bp3;
                float ltx = fmaxf(px1, tx1), lty = fmaxf(py1, ty1);
                float rbx = fminf(px2, tx2), rby = fminf(py2, ty2);
                float iw = fmaxf(rbx - ltx, 0.0f), ih = fmaxf(rby - lty, 0.0f);
                float inter = iw * ih;
                float area_p = (px2 - px1) * (py2 - py1);
                iou0 = inter / (area_p + area_t - inter);
            }
            {   // pred box 1: bp5..bp8
                float bx = bp5 / 14.0f, by = bp6 / 14.0f;
                float px1 = bx - 0.5f * bp7, py1 = by - 0.5f * bp8;
                float px2 = bx + 0.5f * bp7, py2 = by + 0.5f * bp8;
                float ltx = fmaxf(px1, tx1), lty = fmaxf(py1, ty1);
                float rbx = fminf(px2, tx2), rby = fminf(py2, ty2);
                float iw = fmaxf(rbx - ltx, 0.0f), ih = fmaxf(rby - lty, 0.0f);
                float inter = iw * ih;
                float area_p = (px2 - px1) * (py2 - py1);
                iou1 = inter / (area_p + area_t - inter);
            }

            bool sel1 = iou1 > iou0;          // tie -> box 0 (argmax semantics)
            float max_iou = sel1 ? iou1 : iou0;

            float ps0 = sel1 ? bp5 : bp0;
            float ps1 = sel1 ? bp6 : bp1;
            float ps2 = sel1 ? bp7 : bp2;
            float ps3 = sel1 ? bp8 : bp3;
            float ps4 = sel1 ? bp9 : bp4;
            float ts0 = sel1 ? bt5 : bt0;
            float ts1 = sel1 ? bt6 : bt1;
            float ts2 = sel1 ? bt7 : bt2;
            float ts3 = sel1 ? bt8 : bt3;
            float notresp_conf = sel1 ? bp4 : bp9;

            float dconf = ps4 - max_iou;
            float dx = ps0 - ts0, dy = ps1 - ts1;
            float dw = sqrtf(ps2) - sqrtf(ts2);
            float dh = sqrtf(ps3) - sqrtf(ts3);
            float loc = dx * dx + dy * dy + dw * dw + dh * dh;

            loss = 5.0f * loc + 2.0f * dconf * dconf
                 + notresp_conf * notresp_conf + cls;
        }
    } else if (cell < n_cells) {
        // odd trailing cell (not taken when n_cells is even): scalar reads
        loss = cell_loss_ptr(pred + (size_t)cell * 30, targ + (size_t)cell * 30);
    }

    // wave reduce, then 4-wave LDS combine, one partial per block
#pragma unroll
    for (int off = 32; off > 0; off >>= 1)
        loss += __shfl_down(loss, off, 64);

    __shared__ float wsum[BLOCK / 64];
    const int lane = threadIdx.x & 63;
    const int wid  = threadIdx.x >> 6;
    if (lane == 0) wsum[wid] = loss;
    __syncthreads();
    if (threadIdx.x == 0)
        block_sums[blockIdx.x] = wsum[0] + wsum[1] + wsum[2] + wsum[3];
}

__global__ __launch_bounds__(1024) void yolo_reduce_kernel(
    const float* __restrict__ block_sums, int n, double inv_batch,
    float* __restrict__ out)
{
    double acc = 0.0;
    for (int i = threadIdx.x; i < n; i += 1024)
        acc += (double)block_sums[i];
#pragma unroll
    for (int off = 32; off > 0; off >>= 1)
        acc += __shfl_down(acc, off, 64);

    __shared__ double wsum[16];
    int lane = threadIdx.x & 63;
    int wid  = threadIdx.x >> 6;
    if (lane == 0) wsum[wid] = acc;
    __syncthreads();
    if (threadIdx.x == 0) {
        double s = 0.0;
#pragma unroll
        for (int w = 0; w < 16; ++w) s += wsum[w];
        out[0] = (float)(s * inv_batch);
    }
}

extern "C" void kernel_launch(void* const* d_in, const int* in_sizes, int n_in,
                              void* d_out, int out_size, void* d_ws, size_t ws_size,
                              hipStream_t stream) {
    const float* pred = (const float*)d_in[0];
    const float* targ = (const float*)d_in[1];
    float* out = (float*)d_out;
    float* block_sums = (float*)d_ws;   // n_blocks floats, fully written

    int n_elems  = in_sizes[0];         // B*14*14*30
    int n_cells  = n_elems / 30;        // B*196
    int n_batch  = n_cells / (14 * 14); // B
    int n_blocks = (n_cells + BLOCK - 1) / BLOCK;   // 1568 for B=2048

    yolo_cell_kernel<<<n_blocks, BLOCK, 0, stream>>>(pred, targ, block_sums, n_cells);
    yolo_reduce_kernel<<<1, 1024, 0, stream>>>(block_sums, n_blocks,
                                               1.0 / (double)n_batch, out);
}